// Round 6
// baseline (148.888 us; speedup 1.0000x reference)
//
#include <hip/hip_runtime.h>
#include <hip/hip_bf16.h>
#include <stdint.h>

// GAT: B=4, N=2048, F_IN=F_OUT=256, H=4
#define H 4
#define BB 4
#define NN 2048
#define FIN 256
#define FOUT 256
#define M_TOT (BB*NN)   // 8192
#define LOG2E 1.44269504f

typedef float f32x4 __attribute__((ext_vector_type(4)));
typedef short s16x8 __attribute__((ext_vector_type(8)));
typedef unsigned int u32;

static __device__ __forceinline__ short f2bf(float f) {
    return __builtin_bit_cast(short, __float2bfloat16(f));
}
static __device__ __forceinline__ float bf2f(short u) {
    unsigned x = ((unsigned)(unsigned short)u) << 16;
    return __builtin_bit_cast(float, x);
}
// async global->LDS, 16B per lane (dest = wave-uniform base + lane*16)
static __device__ __forceinline__ void glds16(const void* g, void* l) {
    __builtin_amdgcn_global_load_lds(
        (const __attribute__((address_space(1))) u32*)(g),
        (__attribute__((address_space(3))) u32*)(l), 16, 0, 0);
}

// tTs element address (shorts): LDS-image layout, 32KB tile per (h,b,jt)
// tile = [o:256][8 chunks of 8 shorts], chunk XOR-swizzled by o&7
static __device__ __forceinline__ size_t tts_addr(int h, int b, int o, int j) {
    return ((size_t)((h * 4 + b) * 32 + (j >> 6))) * 16384
         + o * 64 + ((((j >> 3) & 7) ^ (o & 7)) << 3) + (j & 7);
}

// ---------------- prep: W[h][k][o] -> WT[h][o][k] (bf16) ----------------
__global__ __launch_bounds__(256) void k_wt(const float* __restrict__ W, short* __restrict__ WT) {
    __shared__ float lds[64][65];
    int bid = blockIdx.x;
    int h = bid >> 4, kt = (bid >> 2) & 3, ot = bid & 3;
    int kb = kt * 64, ob = ot * 64;
    int tx = threadIdx.x & 63, ty = threadIdx.x >> 6;
#pragma unroll
    for (int r = 0; r < 16; ++r) {
        int k_l = ty + r * 4;
        lds[tx][k_l] = W[(size_t)(h * FIN + kb + k_l) * FOUT + ob + tx];
    }
    __syncthreads();
#pragma unroll
    for (int r = 0; r < 16; ++r) {
        int o_l = ty + r * 4;
        WT[(size_t)(h * FOUT + ob + o_l) * FIN + kb + tx] = f2bf(lds[o_l][tx]);
    }
}

// ---------------- prep: q[h][f] = sum_o W[h][f][o]*a[h][o] ----------------
__global__ __launch_bounds__(256) void k_q(const float* __restrict__ W, const float* __restrict__ a,
                                           float* __restrict__ q) {
    int wv = (blockIdx.x * 256 + threadIdx.x) >> 6;  // 0..1023
    int lane = threadIdx.x & 63;
    int h = wv >> 8, f = wv & 255;
    float4 w4 = *(const float4*)(W + (size_t)(h * FIN + f) * FOUT + lane * 4);
    float4 a4 = *(const float4*)(a + h * FOUT + lane * 4);
    float d = w4.x * a4.x + w4.y * a4.y + w4.z * a4.z + w4.w * a4.w;
#pragma unroll
    for (int off = 32; off; off >>= 1) d += __shfl_xor(d, off);
    if (lane == 0) q[h * FIN + f] = d;
}

// ---------------- prep: c[h] = b[h] . a[h] ----------------
__global__ __launch_bounds__(256) void k_c(const float* __restrict__ bvec, const float* __restrict__ a,
                                           float* __restrict__ c) {
    int h = threadIdx.x >> 6, lane = threadIdx.x & 63;
    float4 b4 = *(const float4*)(bvec + h * FOUT + lane * 4);
    float4 a4 = *(const float4*)(a + h * FOUT + lane * 4);
    float d = b4.x * a4.x + b4.y * a4.y + b4.z * a4.z + b4.w * a4.w;
#pragma unroll
    for (int off = 32; off; off >>= 1) d += __shfl_xor(d, off);
    if (lane == 0) c[h] = d;
}

// ---------------- scores (exact fp32) + X->bf16 conversion (fused) ----------------
__global__ __launch_bounds__(256) void k_s(const float* __restrict__ X, const float* __restrict__ q,
                                           const float* __restrict__ c, float* __restrict__ s,
                                           short* __restrict__ Xbf) {
    int m = blockIdx.x * 4 + (threadIdx.x >> 6);
    int lane = threadIdx.x & 63;
    float4 xv = *(const float4*)(X + (size_t)m * FIN + lane * 4);
    short4 xb;
    xb.x = f2bf(xv.x); xb.y = f2bf(xv.y); xb.z = f2bf(xv.z); xb.w = f2bf(xv.w);
    *(short4*)(Xbf + (size_t)m * FIN + lane * 4) = xb;
#pragma unroll
    for (int h = 0; h < H; ++h) {
        float4 qv = *(const float4*)(q + h * FIN + lane * 4);
        float d = xv.x * qv.x + xv.y * qv.y + xv.z * qv.z + xv.w * qv.w;
#pragma unroll
        for (int off = 32; off; off >>= 1) d += __shfl_xor(d, off);
        if (lane == 0) s[h * M_TOT + m] = d + c[h];
    }
}

// ---------------- bias -> edge mask bits + per-row masked max of s_j ----------------
// one wave per (b,i) row; lane covers j = lane*32..lane*32+31.
// mx[h][b*N+i] = max over masked j of s[h][b][j]  (always >-inf: self-loop)
__global__ __launch_bounds__(256) void k_maskmax(const float* __restrict__ bias, const float* __restrict__ s,
                                                 unsigned* __restrict__ mask, float* __restrict__ mx) {
    int w = threadIdx.x >> 6, lane = threadIdx.x & 63;
    int row = blockIdx.x * 4 + w;          // 0..8191 = b*N + i
    const float* bp = bias + (size_t)row * NN + lane * 32;
    unsigned bits = 0;
#pragma unroll
    for (int k = 0; k < 8; ++k) {
        float4 v = *(const float4*)(bp + k * 4);
        bits |= (v.x > -1.f ? 1u : 0u) << (k * 4 + 0);
        bits |= (v.y > -1.f ? 1u : 0u) << (k * 4 + 1);
        bits |= (v.z > -1.f ? 1u : 0u) << (k * 4 + 2);
        bits |= (v.w > -1.f ? 1u : 0u) << (k * 4 + 3);
    }
    mask[(size_t)row * 64 + lane] = bits;
    int b = row >> 11;
#pragma unroll
    for (int h = 0; h < H; ++h) {
        const float* sp = s + h * M_TOT + b * NN + lane * 32;
        float m = -3e38f;
#pragma unroll
        for (int k = 0; k < 8; ++k) {
            float4 sv = *(const float4*)(sp + k * 4);
            m = fmaxf(m, ((bits >> (k * 4 + 0)) & 1u) ? sv.x : -3e38f);
            m = fmaxf(m, ((bits >> (k * 4 + 1)) & 1u) ? sv.y : -3e38f);
            m = fmaxf(m, ((bits >> (k * 4 + 2)) & 1u) ? sv.z : -3e38f);
            m = fmaxf(m, ((bits >> (k * 4 + 3)) & 1u) ? sv.w : -3e38f);
        }
#pragma unroll
        for (int off = 32; off; off >>= 1) m = fmaxf(m, __shfl_xor(m, off));
        if (lane == 0) mx[h * M_TOT + row] = m;
    }
}

// ---------------- tTs = bf16(X@W + b), written in LDS-image swizzled layout ----------------
__global__ __launch_bounds__(256) void k_gemm_t(const short* __restrict__ WT, const short* __restrict__ Xbf,
                                                const float* __restrict__ bvec, short* __restrict__ tTs) {
    int h = blockIdx.z;
    int ob = blockIdx.y * 64;
    int mb = blockIdx.x * 128;
    int lane = threadIdx.x & 63, w = threadIdx.x >> 6;
    int r16 = lane & 15, g = lane >> 4;
    int mw = mb + w * 32;
    f32x4 acc[4][2] = {};
    for (int k = 0; k < FIN; k += 32) {
        s16x8 afr[4], bfr[2];
#pragma unroll
        for (int fa = 0; fa < 4; ++fa)
            afr[fa] = *(const s16x8*)(WT + (size_t)(h * FOUT + ob + fa * 16 + r16) * FIN + k + g * 8);
#pragma unroll
        for (int fb = 0; fb < 2; ++fb)
            bfr[fb] = *(const s16x8*)(Xbf + (size_t)(mw + fb * 16 + r16) * FIN + k + g * 8);
#pragma unroll
        for (int fa = 0; fa < 4; ++fa)
#pragma unroll
            for (int fb = 0; fb < 2; ++fb)
                acc[fa][fb] = __builtin_amdgcn_mfma_f32_16x16x32_bf16(afr[fa], bfr[fb], acc[fa][fb], 0, 0, 0);
    }
#pragma unroll
    for (int fa = 0; fa < 4; ++fa) {
#pragma unroll
        for (int r = 0; r < 4; ++r) {
            int o = ob + fa * 16 + g * 4 + r;
            float bv = bvec[h * FOUT + o];
#pragma unroll
            for (int fb = 0; fb < 2; ++fb) {
                int m = mw + fb * 16 + r16;
                int bb = m >> 11, j = m & 2047;
                tTs[tts_addr(h, bb, o, j)] = f2bf(acc[fa][fb][r] + bv);
            }
        }
    }
}

// ---------------- streaming softmax-PV: OT[h][o][m] (bf16) ----------------
// 512 threads = 8 waves (4 qg x 2 par), 128 queries/block, grid 256 = 1/CU.
// No online max (precomputed row max mx). l computed by MFMA ones-row.
// Triple-buffered glds staging, counted vmcnt(4), ONE barrier per iteration.
__global__ __launch_bounds__(512, 2) void k_attn(const short* __restrict__ tTs, const float* __restrict__ s,
                                                 const unsigned* __restrict__ mask, const float* __restrict__ mx,
                                                 short* __restrict__ OT) {
    extern __shared__ short smem[];   // 3 x 16384 shorts = 98304 B

    // T1: bijective XCD swizzle (256 blocks, 256%8==0)
    int flat = blockIdx.x + 16 * (blockIdx.y + 4 * blockIdx.z);
    int swz = (flat & 7) * 32 + (flat >> 3);
    int qt = swz & 15, b = (swz >> 4) & 3, h = swz >> 6;
    int ib = qt * 128;

    int tid = threadIdx.x;
    int lane = tid & 63, w = tid >> 6;
    int r16 = lane & 15, g = lane >> 4;
    int qg = w >> 1, par = w & 1;
    int i0 = ib + qg * 32 + r16, i1 = i0 + 16;
    size_t gm = (size_t)b * NN;

    const char* slab = (const char*)(tTs + (size_t)(h * 4 + b) * 32 * 16384);
    const float* srow = s + h * M_TOT + gm;
    float si0 = srow[i0], si1 = srow[i1];
    float mx0 = mx[h * M_TOT + gm + i0];
    float mx1 = mx[h * M_TOT + gm + i1];
    float z0 = si0 + mx0, z1 = si1 + mx1;
    float Mlog0 = fmaxf(z0, 0.2f * z0) * LOG2E;   // = leaky(si+mx)*log2e, the exact row max (scaled)
    float Mlog1 = fmaxf(z1, 0.2f * z1) * LOG2E;
    float siL0 = si0 * LOG2E, siL1 = si1 * LOG2E;
    const unsigned* mk0 = mask + (gm + i0) * 64;
    const unsigned* mk1 = mask + (gm + i1) * 64;

    // LDS read offset (shorts) for A-fragments: row r16 (+f*16), chunk (par*4+g)^(r16&7)
    int rd_base = r16 * 64 + ((((par << 2) + g) ^ (r16 & 7)) << 3);

    f32x4 acc[16][2] = {};
    f32x4 accl[2] = {};            // l accumulator via ones-row MFMA
    s16x8 ones;
#pragma unroll
    for (int e = 0; e < 8; ++e) ones[e] = (short)0x3F80;  // bf16 1.0

    // staging: wave w copies bytes [w*1024 + k*8192, +1024) of the 32KB tile
    auto stage = [&](int tt, int slot) {
        const char* gs = slab + (size_t)tt * 32768 + w * 1024 + (size_t)lane * 16;
        short* ldb = smem + slot * 16384 + w * 512;
        glds16(gs,          ldb);
        glds16(gs +  8192,  ldb + 4096);
        glds16(gs + 16384,  ldb + 8192);
        glds16(gs + 24576,  ldb + 12288);
    };
    float4 psj0, psj1; unsigned pw0, pw1;
    auto preload = [&](int tt) {
        int jw = tt * 64 + par * 32;
        psj0 = *(const float4*)(srow + jw + g * 8);
        psj1 = *(const float4*)(srow + jw + g * 8 + 4);
        pw0 = mk0[tt * 2 + par];
        pw1 = mk1[tt * 2 + par];
    };

    stage(0, 0);
    preload(0);
    int cur = 0;

    for (int t = 0; t < 32; ++t) {
        int nxt = (cur == 2) ? 0 : cur + 1;
        if (t < 31) stage(t + 1, nxt);

        // ---- scores from preloaded regs (pure VALU, no cross-lane) ----
        float sjv[8] = {psj0.x, psj0.y, psj0.z, psj0.w, psj1.x, psj1.y, psj1.z, psj1.w};
        unsigned b0 = pw0 >> (g * 8), b1 = pw1 >> (g * 8);
        s16x8 pb0, pb1;
#pragma unroll
        for (int e = 0; e < 8; ++e) {
            float yL0 = fmaf(sjv[e], LOG2E, siL0);
            float yL1 = fmaf(sjv[e], LOG2E, siL1);
            float ly0 = fmaxf(yL0, 0.2f * yL0);
            float ly1 = fmaxf(yL1, 0.2f * yL1);
            float a0 = ((b0 >> e) & 1u) ? (ly0 - Mlog0) : -200.f;  // <= 0 always
            float a1 = ((b1 >> e) & 1u) ? (ly1 - Mlog1) : -200.f;
            pb0[e] = f2bf(__builtin_amdgcn_exp2f(a0));
            pb1[e] = f2bf(__builtin_amdgcn_exp2f(a1));
        }

        __builtin_amdgcn_sched_barrier(0);
        asm volatile("s_waitcnt vmcnt(4)" ::: "memory");   // tile t drained (<=4 = stage(t+1))
        __builtin_amdgcn_s_barrier();
        __builtin_amdgcn_sched_barrier(0);

        // ---- PV MFMAs: 16 A-frags x 2 query-frags + ones-row (l) ----
        const short* bt = smem + cur * 16384;
        __builtin_amdgcn_s_setprio(1);
#pragma unroll
        for (int f = 0; f < 16; ++f) {
            s16x8 af = *(const s16x8*)(bt + f * 1024 + rd_base);
            acc[f][0] = __builtin_amdgcn_mfma_f32_16x16x32_bf16(af, pb0, acc[f][0], 0, 0, 0);
            acc[f][1] = __builtin_amdgcn_mfma_f32_16x16x32_bf16(af, pb1, acc[f][1], 0, 0, 0);
        }
        accl[0] = __builtin_amdgcn_mfma_f32_16x16x32_bf16(ones, pb0, accl[0], 0, 0, 0);
        accl[1] = __builtin_amdgcn_mfma_f32_16x16x32_bf16(ones, pb1, accl[1], 0, 0, 0);
        __builtin_amdgcn_s_setprio(0);

        if (t < 31) preload(t + 1);   // latency hides until next iter's scores
        cur = nxt;
    }

    // ---- epilogue: par-pair partial-sum merge (same M => plain add), store bf16 O^T ----
    __syncthreads();   // protect tile buffers from laggard readers before reuse as exchange
    f32x4* ex = (f32x4*)smem;   // [qg*17 + f][lane], two rounds (qf=0,1): 69632 B
#pragma unroll
    for (int qf = 0; qf < 2; ++qf) {
        if (par) {
#pragma unroll
            for (int f = 0; f < 16; ++f) ex[(qg * 17 + f) * 64 + lane] = acc[f][qf];
            ex[(qg * 17 + 16) * 64 + lane] = accl[qf];
        }
        __syncthreads();
        if (!par) {
            float lsum = accl[qf][0] + ex[(qg * 17 + 16) * 64 + lane][0];
            float inv = 1.f / lsum;
            int iq = qf ? i1 : i0;
            size_t base = (size_t)h * FOUT * M_TOT + gm + iq;
#pragma unroll
            for (int f = 0; f < 16; ++f) {
                f32x4 v = acc[f][qf] + ex[(qg * 17 + f) * 64 + lane];
#pragma unroll
                for (int rr = 0; rr < 4; ++rr) {
                    OT[base + (size_t)(f * 16 + g * 4 + rr) * M_TOT] = f2bf(v[rr] * inv);
                }
            }
        }
        __syncthreads();
    }
}

// ---------------- head mean + transpose: out[m][o] = 0.25 * sum_h OT[h][o][m] ----------------
__global__ __launch_bounds__(256) void k_reduce(const short* __restrict__ OT, float* __restrict__ out) {
    __shared__ float lds[32][72];
    int mb = blockIdx.x * 64, obt = blockIdx.y * 32;
    int tid = threadIdx.x;
    {
        int o_l = tid >> 3;        // 0..31
        int m_l = (tid & 7) * 8;   // 0..56
        float acc[8] = {};
#pragma unroll
        for (int h = 0; h < H; ++h) {
            s16x8 v = *(const s16x8*)(OT + (size_t)(h * FOUT + obt + o_l) * M_TOT + mb + m_l);
#pragma unroll
            for (int e = 0; e < 8; ++e) acc[e] += bf2f(v[e]);
        }
#pragma unroll
        for (int e = 0; e < 8; ++e) lds[o_l][m_l + e] = acc[e] * 0.25f;
    }
    __syncthreads();
    {
        int m_l = tid >> 2;        // 0..63
        int o_l = (tid & 3) * 8;   // 0,8,16,24
        float4 v0, v1;
        v0.x = lds[o_l + 0][m_l]; v0.y = lds[o_l + 1][m_l];
        v0.z = lds[o_l + 2][m_l]; v0.w = lds[o_l + 3][m_l];
        v1.x = lds[o_l + 4][m_l]; v1.y = lds[o_l + 5][m_l];
        v1.z = lds[o_l + 6][m_l]; v1.w = lds[o_l + 7][m_l];
        float* dst = out + (size_t)(mb + m_l) * FOUT + obt + o_l;
        *(float4*)dst = v0;
        *(float4*)(dst + 4) = v1;
    }
}

extern "C" void kernel_launch(void* const* d_in, const int* in_sizes, int n_in,
                              void* d_out, int out_size, void* d_ws, size_t ws_size,
                              hipStream_t stream) {
    const float* X    = (const float*)d_in[0];  // [B,N,FIN]
    const float* bias = (const float*)d_in[1];  // [B,N,N]
    const float* W    = (const float*)d_in[2];  // [H,FIN,FOUT]
    const float* a    = (const float*)d_in[3];  // [H,FOUT]
    const float* bvec = (const float*)d_in[4];  // [H,FOUT]
    float* out = (float*)d_out;                 // [B,N,FOUT] f32

    // workspace layout (~40 MB high-water, same as round 2/4)
    char* ws = (char*)d_ws;
    short*    Xbf  = (short*)ws;                               //  4 MB  [8192][256] bf16
    short*    WT   = (short*)(ws + (4u << 20));                // 512 KB [H][256][256] bf16
    float*    q    = (float*)(ws + (4u << 20) + (768u << 10)); //  4 KB
    float*    c    = q + H * FIN;                              // 16 B
    float*    s    = (float*)(ws + (5u << 20));                // 128 KB [H][8192]
    float*    mxp  = (float*)(ws + (5u << 20) + (256u << 10)); // 128 KB [H][8192] row max
    short*    tTs  = (short*)(ws + (6u << 20));                // 16 MB  swizzled tile images
    short*    OT   = (short*)(ws + (22u << 20));               // 16 MB  [H][256][8192] bf16
    unsigned* mask = (unsigned*)(ws + (38u << 20));            //  2 MB  [B][N][N/32] bits

    k_wt<<<64, 256, 0, stream>>>(W, WT);
    k_q<<<256, 256, 0, stream>>>(W, a, q);
    k_c<<<1, 256, 0, stream>>>(bvec, a, c);
    k_s<<<2048, 256, 0, stream>>>(X, q, c, s, Xbf);
    k_maskmax<<<2048, 256, 0, stream>>>(bias, s, mask, mxp);
    k_gemm_t<<<dim3(64, 4, 4), 256, 0, stream>>>(WT, Xbf, bvec, tTs);
    k_attn<<<dim3(16, 4, 4), 512, 98304, stream>>>(tTs, s, mask, mxp, OT);
    k_reduce<<<dim3(128, 8), 256, 0, stream>>>(OT, out);
}